// Round 16
// baseline (122.583 us; speedup 1.0000x reference)
//
#include <hip/hip_runtime.h>

#define M_ROWS 16384
#define N_CODES 8192
#define K_DIM   256
#define NSPLIT  16
#define SCAP    16384
#define TAU     0.05f

typedef _Float16 half8 __attribute__((ext_vector_type(8)));
typedef float floatx16 __attribute__((ext_vector_type(16)));

#define GLL16(g, l) __builtin_amdgcn_global_load_lds(                         \
    (const __attribute__((address_space(1))) void*)(g),                       \
    (__attribute__((address_space(3))) void*)(l), 16, 0, 0)

#define MFMA16(a, b, c) __builtin_amdgcn_mfma_f32_32x32x16_f16(a, b, c, 0, 0, 0)
#define SCB __builtin_amdgcn_sched_barrier(0)

// ---- fused pack: codebook h-only + en2 + per-split counters zero; x h-only ----
__global__ void pack_all(const float* __restrict__ x, const float* __restrict__ cb,
                         _Float16* __restrict__ Apack, _Float16* __restrict__ Bpack,
                         float* __restrict__ en2, int* __restrict__ cntS) {
  const int bid = blockIdx.x;
  const int tid = threadIdx.x;
  if (bid == 0 && tid < NSPLIT) cntS[tid] = 0;
  if (bid < 1024) {
    const int t = bid * 256 + tid;
    const int C = t >> 5, G = t & 31;
    const int ct = C >> 5, r32 = C & 31;
    const int kc = G >> 2, g2 = G & 3, ks = g2 >> 1, lh = g2 & 1;
    const float* src = cb + (size_t)C * K_DIM + G * 8;
    half8 hv;
    float ss = 0.f;
#pragma unroll
    for (int j = 0; j < 8; ++j) {
      const float v = src[j];
      hv[j] = (_Float16)v;
      ss += v * v;
    }
    ss += __shfl_xor(ss, 1, 32); ss += __shfl_xor(ss, 2, 32);
    ss += __shfl_xor(ss, 4, 32); ss += __shfl_xor(ss, 8, 32);
    ss += __shfl_xor(ss, 16, 32);
    if (G == 0) en2[C] = 0.5f * ss;
    _Float16* blob = Apack + ((size_t)ct * 8 + kc) * 1024;
    const int off = ((ks * 2 + lh) * 32 + r32) * 8;
    *reinterpret_cast<half8*>(blob + off) = hv;
  } else {
    const int t = (bid - 1024) * 256 + tid;
    const int R = t >> 5, G = t & 31;
    const int rt = R >> 7, r = R & 127, jt = r >> 5, rr = r & 31;
    const int kc = G >> 2, g2 = G & 3, ks = g2 >> 1, lh = g2 & 1;
    const float* src = x + (size_t)R * K_DIM + G * 8;
    half8 hv;
#pragma unroll
    for (int j = 0; j < 8; ++j) hv[j] = (_Float16)src[j];
    _Float16* blob = Bpack + ((size_t)rt * 8 + kc) * 4096;
    const int off = ((jt * 2 + ks) * 2 + lh) * 256 + rr * 8;
    *reinterpret_cast<half8*>(blob + off) = hv;
  }
}

// ---- barrier-free h-only distance kernel + per-wave chunk rotation ----
// wave wv walks chunks in order (c + 2*wv) & 7: co-resident waves are
// phase-shifted so epilogue VALU overlaps other waves' MFMA (m114).
__global__ __launch_bounds__(256, 2)
void vq_dist(const _Float16* __restrict__ Apack, const _Float16* __restrict__ Bpack,
             const float* __restrict__ en2, float* __restrict__ candV,
             int* __restrict__ candI, float* __restrict__ cand2) {
  __shared__ _Float16 ldsB[32768];   // 64KB

  const int tid = threadIdx.x;
  const int wv = tid >> 6, lane = tid & 63;
  const int l31 = lane & 31, lh = lane >> 5;
  const int rot = wv * 2;              // per-wave chunk phase

  const int lid = blockIdx.x;          // 0..511
  const int xcd = lid & 7, q = lid >> 3;
  const int cs = xcd >> 1;             // 0..3 (A-quarter pinned per XCD pair)
  const int bx = q * 2 + (xcd & 1);    // 0..127

  const _Float16* gB = Bpack + (size_t)bx * 32768;
#pragma unroll
  for (int s = 0; s < 16; ++s)
    GLL16(gB + (s * 256 + tid) * 8, ldsB + (s * 256 + tid) * 8);

  const int tbase = (cs * 4 + wv) * 16;
  half8 a[2][2][2];   // [parity][it][ks]
  {
    const _Float16* gA0 = Apack + (size_t)(tbase + rot * 2) * 8192;
#pragma unroll
    for (int it = 0; it < 2; ++it)
#pragma unroll
      for (int ks = 0; ks < 2; ++ks)
        a[0][it][ks] = *reinterpret_cast<const half8*>(
            gA0 + (size_t)it * 8192 + ((ks * 2 + lh) * 32 + l31) * 8);
  }

  asm volatile("s_waitcnt vmcnt(4)" ::: "memory");
  SCB;
  __builtin_amdgcn_s_barrier();        // only block barrier
  SCB;

  float b1[4] = {-3.0e38f, -3.0e38f, -3.0e38f, -3.0e38f};
  float b2[4] = {-3.0e38f, -3.0e38f, -3.0e38f, -3.0e38f};
  int i1[4] = {0, 0, 0, 0};

  for (int c = 0; c < 8; ++c) {
    const int cc = (c + rot) & 7;
    const int t0 = tbase + cc * 2;
    floatx16 acc[2][4] = {};
#pragma unroll
    for (int kc = 0; kc < 8; ++kc) {
      const int par = kc & 1, npar = par ^ 1;
      if (!(c == 7 && kc == 7)) {
        const int ncc = (c + 1 + rot) & 7;
        const int nt0 = (kc < 7) ? t0 : (tbase + ncc * 2);
        const int nkc = (kc < 7) ? (kc + 1) : 0;
        const _Float16* gA = Apack + ((size_t)nt0 * 8 + nkc) * 1024;
#pragma unroll
        for (int it = 0; it < 2; ++it)
#pragma unroll
          for (int ks = 0; ks < 2; ++ks)
            a[npar][it][ks] = *reinterpret_cast<const half8*>(
                gA + (size_t)it * 8192 + ((ks * 2 + lh) * 32 + l31) * 8);
      }
      SCB;
      half8 b[4][2];
#pragma unroll
      for (int jt = 0; jt < 4; ++jt)
#pragma unroll
        for (int ks = 0; ks < 2; ++ks)
          b[jt][ks] = *reinterpret_cast<const half8*>(
              ldsB + kc * 4096 + ((jt * 2 + ks) * 2 + lh) * 256 + l31 * 8);
      __builtin_amdgcn_s_setprio(1);
#pragma unroll
      for (int ks = 0; ks < 2; ++ks)
#pragma unroll
        for (int it = 0; it < 2; ++it)
#pragma unroll
          for (int jt = 0; jt < 4; ++jt)
            acc[it][jt] = MFMA16(a[par][it][ks], b[jt][ks], acc[it][jt]);
      __builtin_amdgcn_s_setprio(0);
    }

#pragma unroll
    for (int it = 0; it < 2; ++it) {
      const int code0 = (t0 + it) * 32;
      const float* ep = en2 + code0 + 4 * lh;
      const float4 e0 = *reinterpret_cast<const float4*>(ep);
      const float4 e1 = *reinterpret_cast<const float4*>(ep + 8);
      const float4 e2 = *reinterpret_cast<const float4*>(ep + 16);
      const float4 e3 = *reinterpret_cast<const float4*>(ep + 24);
      const float ev[16] = {e0.x, e0.y, e0.z, e0.w, e1.x, e1.y, e1.z, e1.w,
                            e2.x, e2.y, e2.z, e2.w, e3.x, e3.y, e3.z, e3.w};
#pragma unroll
      for (int reg = 0; reg < 16; ++reg) {
        const int code = code0 + (reg & 3) + 8 * (reg >> 2) + 4 * lh;
#pragma unroll
        for (int jt = 0; jt < 4; ++jt) {
          const float v = acc[it][jt][reg] - ev[reg];
          b2[jt] = fmaxf(b2[jt], fminf(v, b1[jt]));
          i1[jt] = (v > b1[jt]) ? code : i1[jt];
          b1[jt] = fmaxf(b1[jt], v);
        }
      }
    }
  }

  // merge lane <-> lane^32 (same rows, disjoint codes)
#pragma unroll
  for (int jt = 0; jt < 4; ++jt) {
    const float o1 = __shfl_xor(b1[jt], 32, 64);
    const int oi = __shfl_xor(i1[jt], 32, 64);
    const float o2 = __shfl_xor(b2[jt], 32, 64);
    const float lose = fminf(b1[jt], o1);
    i1[jt] = (b1[jt] >= o1) ? i1[jt] : oi;
    b1[jt] = fmaxf(b1[jt], o1);
    b2[jt] = fmaxf(fmaxf(b2[jt], o2), lose);
  }

  if (lane < 32) {
    const int split = cs * 4 + wv;
#pragma unroll
    for (int jt = 0; jt < 4; ++jt) {
      const int row = bx * 128 + jt * 32 + l31;
      candV[(size_t)split * M_ROWS + row] = b1[jt];
      candI[(size_t)split * M_ROWS + row] = i1[jt];
      cand2[(size_t)split * M_ROWS + row] = b2[jt];
    }
  }
}

// ---- merge 16 splits -> packed key; enqueue risky rows onto per-split lists ----
__global__ void vq_reduce(const float* __restrict__ candV, const int* __restrict__ candI,
                          const float* __restrict__ cand2, int* __restrict__ cntS,
                          int* __restrict__ riskyS, unsigned long long* __restrict__ key) {
  const int row = blockIdx.x * 256 + threadIdx.x;
  float v[NSPLIT];
#pragma unroll
  for (int s = 0; s < NSPLIT; ++s) v[s] = candV[(size_t)s * M_ROWS + row];
  float b1 = v[0];
  int i1 = candI[row];
  float b2 = cand2[row];
#pragma unroll
  for (int s = 1; s < NSPLIT; ++s) {
    const int ii = candI[(size_t)s * M_ROWS + row];
    const float v2 = cand2[(size_t)s * M_ROWS + row];
    const float lose = fminf(b1, v[s]);
    i1 = (v[s] > b1) ? ii : i1;
    b1 = fmaxf(b1, v[s]);
    b2 = fmaxf(fmaxf(b2, v2), lose);
  }
  if (b1 - b2 < TAU) {
    key[row] = 0ull;
    const float thr = b1 - TAU;
#pragma unroll
    for (int s = 0; s < NSPLIT; ++s) {
      if (v[s] > thr) {
        const int p = atomicAdd(&cntS[s], 1);
        riskyS[(size_t)s * SCAP + p] = row;
      }
    }
  } else {
    unsigned u = __float_as_uint(b1);
    u ^= (u >> 31) ? 0xFFFFFFFFu : 0x80000000u;
    key[row] = ((unsigned long long)u << 32) | (unsigned)(N_CODES - 1 - i1);
  }
}

// ---- exact fp32 rescore, split-filtered, 4 row-stripes ----
__global__ __launch_bounds__(256)
void vq_refine(const float* __restrict__ x, const float* __restrict__ cb,
               const float* __restrict__ en2, const int* __restrict__ cntS,
               const int* __restrict__ riskyS, unsigned long long* __restrict__ key) {
  __shared__ float cbs[32][260];
  __shared__ float xs[8][260];
  __shared__ int rowS[8];
  const int split = blockIdx.x >> 4;
  const int n = cntS[split];
  if (n == 0) return;
  const int tid = threadIdx.x;
  const int cBase = split * 512 + (blockIdx.x & 15) * 32;
  const int* list = riskyS + (size_t)split * SCAP;
  const int cl = tid >> 3, rs = tid & 7;
#pragma unroll
  for (int q = 0; q < 32; ++q) cbs[q][tid] = cb[(size_t)(cBase + q) * K_DIM + tid];
  const float e_c = en2[cBase + cl];
  for (int t0 = blockIdx.y * 8; t0 < n; t0 += 32) {
    __syncthreads();
    if (tid < 8) {
      const int ti = t0 + tid;
      rowS[tid] = list[ti < n ? ti : n - 1];
    }
    __syncthreads();
#pragma unroll
    for (int r = 0; r < 8; ++r) xs[r][tid] = x[(size_t)rowS[r] * K_DIM + tid];
    __syncthreads();
    float s0 = 0.f, s1 = 0.f;
#pragma unroll 4
    for (int k4 = 0; k4 < 64; k4 += 2) {
      const float4 c0 = *reinterpret_cast<const float4*>(&cbs[cl][k4 * 4]);
      const float4 x0 = *reinterpret_cast<const float4*>(&xs[rs][k4 * 4]);
      const float4 c1 = *reinterpret_cast<const float4*>(&cbs[cl][k4 * 4 + 4]);
      const float4 x1 = *reinterpret_cast<const float4*>(&xs[rs][k4 * 4 + 4]);
      s0 = fmaf(x0.x, c0.x, s0); s0 = fmaf(x0.y, c0.y, s0);
      s0 = fmaf(x0.z, c0.z, s0); s0 = fmaf(x0.w, c0.w, s0);
      s1 = fmaf(x1.x, c1.x, s1); s1 = fmaf(x1.y, c1.y, s1);
      s1 = fmaf(x1.z, c1.z, s1); s1 = fmaf(x1.w, c1.w, s1);
    }
    const float sc = (s0 + s1) - e_c;
    unsigned u = __float_as_uint(sc);
    u ^= (u >> 31) ? 0xFFFFFFFFu : 0x80000000u;
    unsigned long long k64 =
        ((unsigned long long)u << 32) | (unsigned)(N_CODES - 1 - (cBase + cl));
    {
      unsigned long long o;
      o = __shfl_xor(k64, 8, 64);  if (o > k64) k64 = o;
      o = __shfl_xor(k64, 16, 64); if (o > k64) k64 = o;
      o = __shfl_xor(k64, 32, 64); if (o > k64) k64 = o;
    }
    if (((tid >> 3) & 7) == 0) atomicMax(key + rowS[rs], k64);
  }
}

// ---- gather z_q from key, write z_q_st + indices, partial loss sums ----
__global__ void vq_gather(const float* __restrict__ x, const float* __restrict__ cb,
                          const unsigned long long* __restrict__ key, float* __restrict__ zq,
                          float* __restrict__ idxf, float* __restrict__ partial) {
  __shared__ float red[256];
  const int g = blockIdx.x * 256 + threadIdx.x;
  const int row = g >> 6;
  const int c4 = g & 63;
  const int idx = N_CODES - 1 - (int)(unsigned)(key[row] & 0xFFFFFFFFull);
  if (c4 == 0) idxf[row] = (float)idx;
  const float4 z = *reinterpret_cast<const float4*>(cb + (size_t)idx * K_DIM + c4 * 4);
  const float4 xv = *reinterpret_cast<const float4*>(x + (size_t)g * 4);
  *reinterpret_cast<float4*>(zq + (size_t)g * 4) = z;
  const float dx = z.x - xv.x, dy = z.y - xv.y, dz = z.z - xv.z, dw = z.w - xv.w;
  red[threadIdx.x] = dx * dx + dy * dy + dz * dz + dw * dw;
  __syncthreads();
  for (int o = 128; o > 0; o >>= 1) {
    if (threadIdx.x < o) red[threadIdx.x] += red[threadIdx.x + o];
    __syncthreads();
  }
  if (threadIdx.x == 0) partial[blockIdx.x] = red[0];
}

__global__ void vq_loss(const float* __restrict__ partial, float* __restrict__ out) {
  __shared__ float red[256];
  float s = 0.f;
  for (int i = threadIdx.x; i < 4096; i += 256) s += partial[i];
  red[threadIdx.x] = s;
  __syncthreads();
  for (int o = 128; o > 0; o >>= 1) {
    if (threadIdx.x < o) red[threadIdx.x] += red[threadIdx.x + o];
    __syncthreads();
  }
  if (threadIdx.x == 0) out[0] = 1.25f * red[0] / 4194304.0f;
}

extern "C" void kernel_launch(void* const* d_in, const int* in_sizes, int n_in,
                              void* d_out, int out_size, void* d_ws, size_t ws_size,
                              hipStream_t stream) {
  const float* x = (const float*)d_in[0];
  const float* cb = (const float*)d_in[1];
  float* out = (float*)d_out;
  float* zq = out;
  float* loss = out + 4194304;
  float* idxf = out + 4194305;

  char* w = (char*)d_ws;
  _Float16* Apack = (_Float16*)w;                      w += (size_t)N_CODES * K_DIM * 2;   // 4MB h
  _Float16* Bpack = (_Float16*)w;                      w += (size_t)M_ROWS * K_DIM * 2;    // 8MB h
  unsigned long long* key = (unsigned long long*)w;    w += (size_t)M_ROWS * 8;
  float* en2 = (float*)w;                              w += (size_t)N_CODES * 4;
  float* candV = (float*)w;                            w += (size_t)M_ROWS * NSPLIT * 4;
  float* cand2 = (float*)w;                            w += (size_t)M_ROWS * NSPLIT * 4;
  int* candI = (int*)w;                                w += (size_t)M_ROWS * NSPLIT * 4;
  int* riskyS = (int*)w;                               w += (size_t)NSPLIT * SCAP * 4;     // 1MB
  int* cntS = (int*)w;                                 w += 64;
  float* part = (float*)w;                             w += 4096 * 4;

  pack_all<<<3072, 256, 0, stream>>>(x, cb, Apack, Bpack, en2, cntS);
  vq_dist<<<512, 256, 0, stream>>>(Apack, Bpack, en2, candV, candI, cand2);
  vq_reduce<<<M_ROWS / 256, 256, 0, stream>>>(candV, candI, cand2, cntS, riskyS, key);
  vq_refine<<<dim3(256, 4), 256, 0, stream>>>(x, cb, en2, cntS, riskyS, key);
  vq_gather<<<4194304 / (256 * 4), 256, 0, stream>>>(x, cb, key, zq, idxf, part);
  vq_loss<<<1, 256, 0, stream>>>(part, loss);
}

// Round 17
// 119.098 us; speedup vs baseline: 1.0293x; 1.0293x over previous
//
#include <hip/hip_runtime.h>

#define M_ROWS 16384
#define N_CODES 8192
#define K_DIM   256
#define NSPLIT  16
#define SCAP    16384
#define TAU     0.05f

typedef _Float16 half8 __attribute__((ext_vector_type(8)));
typedef float floatx16 __attribute__((ext_vector_type(16)));

#define GLL16(g, l) __builtin_amdgcn_global_load_lds(                         \
    (const __attribute__((address_space(1))) void*)(g),                       \
    (__attribute__((address_space(3))) void*)(l), 16, 0, 0)

#define MFMA16(a, b, c) __builtin_amdgcn_mfma_f32_32x32x16_f16(a, b, c, 0, 0, 0)
#define SCB __builtin_amdgcn_sched_barrier(0)

// ---- fused pack: codebook h-only + en2; x h-only + xn (row norms); cnt zero ----
__global__ void pack_all(const float* __restrict__ x, const float* __restrict__ cb,
                         _Float16* __restrict__ Apack, _Float16* __restrict__ Bpack,
                         float* __restrict__ en2, float* __restrict__ xn,
                         int* __restrict__ cntS) {
  const int bid = blockIdx.x;
  const int tid = threadIdx.x;
  if (bid == 0 && tid < NSPLIT) cntS[tid] = 0;
  if (bid < 1024) {
    const int t = bid * 256 + tid;
    const int C = t >> 5, G = t & 31;
    const int ct = C >> 5, r32 = C & 31;
    const int kc = G >> 2, g2 = G & 3, ks = g2 >> 1, lh = g2 & 1;
    const float* src = cb + (size_t)C * K_DIM + G * 8;
    half8 hv;
    float ss = 0.f;
#pragma unroll
    for (int j = 0; j < 8; ++j) {
      const float v = src[j];
      hv[j] = (_Float16)v;
      ss += v * v;
    }
    ss += __shfl_xor(ss, 1, 32); ss += __shfl_xor(ss, 2, 32);
    ss += __shfl_xor(ss, 4, 32); ss += __shfl_xor(ss, 8, 32);
    ss += __shfl_xor(ss, 16, 32);
    if (G == 0) en2[C] = 0.5f * ss;
    _Float16* blob = Apack + ((size_t)ct * 8 + kc) * 1024;
    const int off = ((ks * 2 + lh) * 32 + r32) * 8;
    *reinterpret_cast<half8*>(blob + off) = hv;
  } else {
    const int t = (bid - 1024) * 256 + tid;
    const int R = t >> 5, G = t & 31;
    const int rt = R >> 7, r = R & 127, jt = r >> 5, rr = r & 31;
    const int kc = G >> 2, g2 = G & 3, ks = g2 >> 1, lh = g2 & 1;
    const float* src = x + (size_t)R * K_DIM + G * 8;
    half8 hv;
    float ss = 0.f;
#pragma unroll
    for (int j = 0; j < 8; ++j) {
      const float v = src[j];
      hv[j] = (_Float16)v;
      ss += v * v;
    }
    ss += __shfl_xor(ss, 1, 32); ss += __shfl_xor(ss, 2, 32);
    ss += __shfl_xor(ss, 4, 32); ss += __shfl_xor(ss, 8, 32);
    ss += __shfl_xor(ss, 16, 32);
    if (G == 0) xn[R] = ss;
    _Float16* blob = Bpack + ((size_t)rt * 8 + kc) * 4096;
    const int off = ((jt * 2 + ks) * 2 + lh) * 256 + rr * 8;
    *reinterpret_cast<half8*>(blob + off) = hv;
  }
}

// ---- barrier-free h-only distance kernel (byte-exact R15 known-good) ----
__global__ __launch_bounds__(256, 2)
void vq_dist(const _Float16* __restrict__ Apack, const _Float16* __restrict__ Bpack,
             const float* __restrict__ en2, float* __restrict__ candV,
             int* __restrict__ candI, float* __restrict__ cand2) {
  __shared__ _Float16 ldsB[32768];   // 64KB

  const int tid = threadIdx.x;
  const int wv = tid >> 6, lane = tid & 63;
  const int l31 = lane & 31, lh = lane >> 5;

  const int lid = blockIdx.x;          // 0..511
  const int xcd = lid & 7, q = lid >> 3;
  const int cs = xcd >> 1;             // 0..3 (A-quarter pinned per XCD pair)
  const int bx = q * 2 + (xcd & 1);    // 0..127

  const _Float16* gB = Bpack + (size_t)bx * 32768;
#pragma unroll
  for (int s = 0; s < 16; ++s)
    GLL16(gB + (s * 256 + tid) * 8, ldsB + (s * 256 + tid) * 8);

  const int tbase = (cs * 4 + wv) * 16;
  half8 a[2][2][2];   // [parity][it][ks]
  {
    const _Float16* gA0 = Apack + ((size_t)tbase) * 8192;
#pragma unroll
    for (int it = 0; it < 2; ++it)
#pragma unroll
      for (int ks = 0; ks < 2; ++ks)
        a[0][it][ks] = *reinterpret_cast<const half8*>(
            gA0 + (size_t)it * 8192 + ((ks * 2 + lh) * 32 + l31) * 8);
  }

  asm volatile("s_waitcnt vmcnt(4)" ::: "memory");
  SCB;
  __builtin_amdgcn_s_barrier();        // only block barrier
  SCB;

  float b1[4] = {-3.0e38f, -3.0e38f, -3.0e38f, -3.0e38f};
  float b2[4] = {-3.0e38f, -3.0e38f, -3.0e38f, -3.0e38f};
  int i1[4] = {0, 0, 0, 0};

  for (int c = 0; c < 8; ++c) {
    const int t0 = tbase + c * 2;
    floatx16 acc[2][4] = {};
#pragma unroll
    for (int kc = 0; kc < 8; ++kc) {
      const int par = kc & 1, npar = par ^ 1;
      if (!(c == 7 && kc == 7)) {
        const int nt0 = (kc < 7) ? t0 : (t0 + 2);
        const int nkc = (kc < 7) ? (kc + 1) : 0;
        const _Float16* gA = Apack + ((size_t)nt0 * 8 + nkc) * 1024;
#pragma unroll
        for (int it = 0; it < 2; ++it)
#pragma unroll
          for (int ks = 0; ks < 2; ++ks)
            a[npar][it][ks] = *reinterpret_cast<const half8*>(
                gA + (size_t)it * 8192 + ((ks * 2 + lh) * 32 + l31) * 8);
      }
      SCB;
      half8 b[4][2];
#pragma unroll
      for (int jt = 0; jt < 4; ++jt)
#pragma unroll
        for (int ks = 0; ks < 2; ++ks)
          b[jt][ks] = *reinterpret_cast<const half8*>(
              ldsB + kc * 4096 + ((jt * 2 + ks) * 2 + lh) * 256 + l31 * 8);
      __builtin_amdgcn_s_setprio(1);
#pragma unroll
      for (int ks = 0; ks < 2; ++ks)
#pragma unroll
        for (int it = 0; it < 2; ++it)
#pragma unroll
          for (int jt = 0; jt < 4; ++jt)
            acc[it][jt] = MFMA16(a[par][it][ks], b[jt][ks], acc[it][jt]);
      __builtin_amdgcn_s_setprio(0);
    }

#pragma unroll
    for (int it = 0; it < 2; ++it) {
      const int code0 = (t0 + it) * 32;
      const float* ep = en2 + code0 + 4 * lh;
      const float4 e0 = *reinterpret_cast<const float4*>(ep);
      const float4 e1 = *reinterpret_cast<const float4*>(ep + 8);
      const float4 e2 = *reinterpret_cast<const float4*>(ep + 16);
      const float4 e3 = *reinterpret_cast<const float4*>(ep + 24);
      const float ev[16] = {e0.x, e0.y, e0.z, e0.w, e1.x, e1.y, e1.z, e1.w,
                            e2.x, e2.y, e2.z, e2.w, e3.x, e3.y, e3.z, e3.w};
#pragma unroll
      for (int reg = 0; reg < 16; ++reg) {
        const int code = code0 + (reg & 3) + 8 * (reg >> 2) + 4 * lh;
#pragma unroll
        for (int jt = 0; jt < 4; ++jt) {
          const float v = acc[it][jt][reg] - ev[reg];
          b2[jt] = fmaxf(b2[jt], fminf(v, b1[jt]));
          i1[jt] = (v > b1[jt]) ? code : i1[jt];
          b1[jt] = fmaxf(b1[jt], v);
        }
      }
    }
  }

  // merge lane <-> lane^32 (same rows, disjoint codes)
#pragma unroll
  for (int jt = 0; jt < 4; ++jt) {
    const float o1 = __shfl_xor(b1[jt], 32, 64);
    const int oi = __shfl_xor(i1[jt], 32, 64);
    const float o2 = __shfl_xor(b2[jt], 32, 64);
    const float lose = fminf(b1[jt], o1);
    i1[jt] = (b1[jt] >= o1) ? i1[jt] : oi;
    b1[jt] = fmaxf(b1[jt], o1);
    b2[jt] = fmaxf(fmaxf(b2[jt], o2), lose);
  }

  if (lane < 32) {
    const int split = cs * 4 + wv;
#pragma unroll
    for (int jt = 0; jt < 4; ++jt) {
      const int row = bx * 128 + jt * 32 + l31;
      candV[(size_t)split * M_ROWS + row] = b1[jt];
      candI[(size_t)split * M_ROWS + row] = i1[jt];
      cand2[(size_t)split * M_ROWS + row] = b2[jt];
    }
  }
}

// ---- merge 16 splits -> packed key; enqueue risky rows onto per-split lists ----
__global__ void vq_reduce(const float* __restrict__ candV, const int* __restrict__ candI,
                          const float* __restrict__ cand2, int* __restrict__ cntS,
                          int* __restrict__ riskyS, unsigned long long* __restrict__ key) {
  const int row = blockIdx.x * 256 + threadIdx.x;
  float v[NSPLIT];
#pragma unroll
  for (int s = 0; s < NSPLIT; ++s) v[s] = candV[(size_t)s * M_ROWS + row];
  float b1 = v[0];
  int i1 = candI[row];
  float b2 = cand2[row];
#pragma unroll
  for (int s = 1; s < NSPLIT; ++s) {
    const int ii = candI[(size_t)s * M_ROWS + row];
    const float v2 = cand2[(size_t)s * M_ROWS + row];
    const float lose = fminf(b1, v[s]);
    i1 = (v[s] > b1) ? ii : i1;
    b1 = fmaxf(b1, v[s]);
    b2 = fmaxf(fmaxf(b2, v2), lose);
  }
  if (b1 - b2 < TAU) {
    key[row] = 0ull;
    const float thr = b1 - TAU;
#pragma unroll
    for (int s = 0; s < NSPLIT; ++s) {
      if (v[s] > thr) {
        const int p = atomicAdd(&cntS[s], 1);
        riskyS[(size_t)s * SCAP + p] = row;
      }
    }
  } else {
    unsigned u = __float_as_uint(b1);
    u ^= (u >> 31) ? 0xFFFFFFFFu : 0x80000000u;
    key[row] = ((unsigned long long)u << 32) | (unsigned)(N_CODES - 1 - i1);
  }
}

// ---- exact fp32 rescore, split-filtered, 4 row-stripes ----
__global__ __launch_bounds__(256)
void vq_refine(const float* __restrict__ x, const float* __restrict__ cb,
               const float* __restrict__ en2, const int* __restrict__ cntS,
               const int* __restrict__ riskyS, unsigned long long* __restrict__ key) {
  __shared__ float cbs[32][260];
  __shared__ float xs[8][260];
  __shared__ int rowS[8];
  const int split = blockIdx.x >> 4;
  const int n = cntS[split];
  if (n == 0) return;
  const int tid = threadIdx.x;
  const int cBase = split * 512 + (blockIdx.x & 15) * 32;
  const int* list = riskyS + (size_t)split * SCAP;
  const int cl = tid >> 3, rs = tid & 7;
#pragma unroll
  for (int q = 0; q < 32; ++q) cbs[q][tid] = cb[(size_t)(cBase + q) * K_DIM + tid];
  const float e_c = en2[cBase + cl];
  for (int t0 = blockIdx.y * 8; t0 < n; t0 += 32) {
    __syncthreads();
    if (tid < 8) {
      const int ti = t0 + tid;
      rowS[tid] = list[ti < n ? ti : n - 1];
    }
    __syncthreads();
#pragma unroll
    for (int r = 0; r < 8; ++r) xs[r][tid] = x[(size_t)rowS[r] * K_DIM + tid];
    __syncthreads();
    float s0 = 0.f, s1 = 0.f;
#pragma unroll 4
    for (int k4 = 0; k4 < 64; k4 += 2) {
      const float4 c0 = *reinterpret_cast<const float4*>(&cbs[cl][k4 * 4]);
      const float4 x0 = *reinterpret_cast<const float4*>(&xs[rs][k4 * 4]);
      const float4 c1 = *reinterpret_cast<const float4*>(&cbs[cl][k4 * 4 + 4]);
      const float4 x1 = *reinterpret_cast<const float4*>(&xs[rs][k4 * 4 + 4]);
      s0 = fmaf(x0.x, c0.x, s0); s0 = fmaf(x0.y, c0.y, s0);
      s0 = fmaf(x0.z, c0.z, s0); s0 = fmaf(x0.w, c0.w, s0);
      s1 = fmaf(x1.x, c1.x, s1); s1 = fmaf(x1.y, c1.y, s1);
      s1 = fmaf(x1.z, c1.z, s1); s1 = fmaf(x1.w, c1.w, s1);
    }
    const float sc = (s0 + s1) - e_c;
    unsigned u = __float_as_uint(sc);
    u ^= (u >> 31) ? 0xFFFFFFFFu : 0x80000000u;
    unsigned long long k64 =
        ((unsigned long long)u << 32) | (unsigned)(N_CODES - 1 - (cBase + cl));
    {
      unsigned long long o;
      o = __shfl_xor(k64, 8, 64);  if (o > k64) k64 = o;
      o = __shfl_xor(k64, 16, 64); if (o > k64) k64 = o;
      o = __shfl_xor(k64, 32, 64); if (o > k64) k64 = o;
    }
    if (((tid >> 3) & 7) == 0) atomicMax(key + rowS[rs], k64);
  }
}

// ---- gather z_q from key, write z_q_st + indices (no x read, no reduction) ----
__global__ void vq_gather(const float* __restrict__ cb,
                          const unsigned long long* __restrict__ key,
                          float* __restrict__ zq, float* __restrict__ idxf) {
  const int g = blockIdx.x * 256 + threadIdx.x;
  const int row = g >> 6;
  const int c4 = g & 63;
  const int idx = N_CODES - 1 - (int)(unsigned)(key[row] & 0xFFFFFFFFull);
  if (c4 == 0) idxf[row] = (float)idx;
  const float4 z = *reinterpret_cast<const float4*>(cb + (size_t)idx * K_DIM + c4 * 4);
  *reinterpret_cast<float4*>(zq + (size_t)g * 4) = z;
}

// ---- analytic loss: sum over rows of (||x||^2 - 2*score) ----
// score decoded from key's monotone-encoded top-32 bits.
__global__ void vq_loss(const unsigned long long* __restrict__ key,
                        const float* __restrict__ xn, float* __restrict__ out) {
  __shared__ float red[256];
  const int tid = threadIdx.x;
  float s = 0.f;
  for (int i = 0; i < 64; ++i) {
    const int row = i * 256 + tid;
    const unsigned eu = (unsigned)(key[row] >> 32);
    const unsigned fu = (eu & 0x80000000u) ? (eu ^ 0x80000000u) : ~eu;
    s += xn[row] - 2.0f * __uint_as_float(fu);
  }
  red[tid] = s;
  __syncthreads();
  for (int o = 128; o > 0; o >>= 1) {
    if (tid < o) red[tid] += red[tid + o];
    __syncthreads();
  }
  if (tid == 0) out[0] = 1.25f * red[0] / 4194304.0f;
}

extern "C" void kernel_launch(void* const* d_in, const int* in_sizes, int n_in,
                              void* d_out, int out_size, void* d_ws, size_t ws_size,
                              hipStream_t stream) {
  const float* x = (const float*)d_in[0];
  const float* cb = (const float*)d_in[1];
  float* out = (float*)d_out;
  float* zq = out;
  float* loss = out + 4194304;
  float* idxf = out + 4194305;

  char* w = (char*)d_ws;
  _Float16* Apack = (_Float16*)w;                      w += (size_t)N_CODES * K_DIM * 2;   // 4MB h
  _Float16* Bpack = (_Float16*)w;                      w += (size_t)M_ROWS * K_DIM * 2;    // 8MB h
  unsigned long long* key = (unsigned long long*)w;    w += (size_t)M_ROWS * 8;
  float* en2 = (float*)w;                              w += (size_t)N_CODES * 4;
  float* xn = (float*)w;                               w += (size_t)M_ROWS * 4;
  float* candV = (float*)w;                            w += (size_t)M_ROWS * NSPLIT * 4;
  float* cand2 = (float*)w;                            w += (size_t)M_ROWS * NSPLIT * 4;
  int* candI = (int*)w;                                w += (size_t)M_ROWS * NSPLIT * 4;
  int* riskyS = (int*)w;                               w += (size_t)NSPLIT * SCAP * 4;     // 1MB
  int* cntS = (int*)w;                                 w += 64;

  pack_all<<<3072, 256, 0, stream>>>(x, cb, Apack, Bpack, en2, xn, cntS);
  vq_dist<<<512, 256, 0, stream>>>(Apack, Bpack, en2, candV, candI, cand2);
  vq_reduce<<<M_ROWS / 256, 256, 0, stream>>>(candV, candI, cand2, cntS, riskyS, key);
  vq_refine<<<dim3(256, 4), 256, 0, stream>>>(x, cb, en2, cntS, riskyS, key);
  vq_gather<<<4194304 / (256 * 4), 256, 0, stream>>>(cb, key, zq, idxf);
  vq_loss<<<1, 256, 0, stream>>>(key, xn, loss);
}

// Round 19
// 118.421 us; speedup vs baseline: 1.0351x; 1.0057x over previous
//
#include <hip/hip_runtime.h>

#define M_ROWS 16384
#define N_CODES 8192
#define K_DIM   256
#define NSPLIT  16
#define SCAP    16384
#define TAU     0.05f

typedef _Float16 half8 __attribute__((ext_vector_type(8)));
typedef float floatx16 __attribute__((ext_vector_type(16)));

#define GLL16(g, l) __builtin_amdgcn_global_load_lds(                         \
    (const __attribute__((address_space(1))) void*)(g),                       \
    (__attribute__((address_space(3))) void*)(l), 16, 0, 0)

#define MFMA16(a, b, c) __builtin_amdgcn_mfma_f32_32x32x16_f16(a, b, c, 0, 0, 0)
#define SCB __builtin_amdgcn_sched_barrier(0)

// ---- fused pack: codebook h-only + en2; x h-only + xn (row norms); cnt zero ----
__global__ void pack_all(const float* __restrict__ x, const float* __restrict__ cb,
                         _Float16* __restrict__ Apack, _Float16* __restrict__ Bpack,
                         float* __restrict__ en2, float* __restrict__ xn,
                         int* __restrict__ cntS) {
  const int bid = blockIdx.x;
  const int tid = threadIdx.x;
  if (bid == 0 && tid < NSPLIT) cntS[tid] = 0;
  if (bid < 1024) {
    const int t = bid * 256 + tid;
    const int C = t >> 5, G = t & 31;
    const int ct = C >> 5, r32 = C & 31;
    const int kc = G >> 2, g2 = G & 3, ks = g2 >> 1, lh = g2 & 1;
    const float* src = cb + (size_t)C * K_DIM + G * 8;
    half8 hv;
    float ss = 0.f;
#pragma unroll
    for (int j = 0; j < 8; ++j) {
      const float v = src[j];
      hv[j] = (_Float16)v;
      ss += v * v;
    }
    ss += __shfl_xor(ss, 1, 32); ss += __shfl_xor(ss, 2, 32);
    ss += __shfl_xor(ss, 4, 32); ss += __shfl_xor(ss, 8, 32);
    ss += __shfl_xor(ss, 16, 32);
    if (G == 0) en2[C] = 0.5f * ss;
    _Float16* blob = Apack + ((size_t)ct * 8 + kc) * 1024;
    const int off = ((ks * 2 + lh) * 32 + r32) * 8;
    *reinterpret_cast<half8*>(blob + off) = hv;
  } else {
    const int t = (bid - 1024) * 256 + tid;
    const int R = t >> 5, G = t & 31;
    const int rt = R >> 7, r = R & 127, jt = r >> 5, rr = r & 31;
    const int kc = G >> 2, g2 = G & 3, ks = g2 >> 1, lh = g2 & 1;
    const float* src = x + (size_t)R * K_DIM + G * 8;
    half8 hv;
    float ss = 0.f;
#pragma unroll
    for (int j = 0; j < 8; ++j) {
      const float v = src[j];
      hv[j] = (_Float16)v;
      ss += v * v;
    }
    ss += __shfl_xor(ss, 1, 32); ss += __shfl_xor(ss, 2, 32);
    ss += __shfl_xor(ss, 4, 32); ss += __shfl_xor(ss, 8, 32);
    ss += __shfl_xor(ss, 16, 32);
    if (G == 0) xn[R] = ss;
    _Float16* blob = Bpack + ((size_t)rt * 8 + kc) * 4096;
    const int off = ((jt * 2 + ks) * 2 + lh) * 256 + rr * 8;
    *reinterpret_cast<half8*>(blob + off) = hv;
  }
}

// ---- barrier-free h-only distance kernel (byte-exact R15 known-good) ----
__global__ __launch_bounds__(256, 2)
void vq_dist(const _Float16* __restrict__ Apack, const _Float16* __restrict__ Bpack,
             const float* __restrict__ en2, float* __restrict__ candV,
             int* __restrict__ candI, float* __restrict__ cand2) {
  __shared__ _Float16 ldsB[32768];   // 64KB

  const int tid = threadIdx.x;
  const int wv = tid >> 6, lane = tid & 63;
  const int l31 = lane & 31, lh = lane >> 5;

  const int lid = blockIdx.x;          // 0..511
  const int xcd = lid & 7, q = lid >> 3;
  const int cs = xcd >> 1;             // 0..3 (A-quarter pinned per XCD pair)
  const int bx = q * 2 + (xcd & 1);    // 0..127

  const _Float16* gB = Bpack + (size_t)bx * 32768;
#pragma unroll
  for (int s = 0; s < 16; ++s)
    GLL16(gB + (s * 256 + tid) * 8, ldsB + (s * 256 + tid) * 8);

  const int tbase = (cs * 4 + wv) * 16;
  half8 a[2][2][2];   // [parity][it][ks]
  {
    const _Float16* gA0 = Apack + ((size_t)tbase) * 8192;
#pragma unroll
    for (int it = 0; it < 2; ++it)
#pragma unroll
      for (int ks = 0; ks < 2; ++ks)
        a[0][it][ks] = *reinterpret_cast<const half8*>(
            gA0 + (size_t)it * 8192 + ((ks * 2 + lh) * 32 + l31) * 8);
  }

  asm volatile("s_waitcnt vmcnt(4)" ::: "memory");
  SCB;
  __builtin_amdgcn_s_barrier();        // only block barrier
  SCB;

  float b1[4] = {-3.0e38f, -3.0e38f, -3.0e38f, -3.0e38f};
  float b2[4] = {-3.0e38f, -3.0e38f, -3.0e38f, -3.0e38f};
  int i1[4] = {0, 0, 0, 0};

  for (int c = 0; c < 8; ++c) {
    const int t0 = tbase + c * 2;
    floatx16 acc[2][4] = {};
#pragma unroll
    for (int kc = 0; kc < 8; ++kc) {
      const int par = kc & 1, npar = par ^ 1;
      if (!(c == 7 && kc == 7)) {
        const int nt0 = (kc < 7) ? t0 : (t0 + 2);
        const int nkc = (kc < 7) ? (kc + 1) : 0;
        const _Float16* gA = Apack + ((size_t)nt0 * 8 + nkc) * 1024;
#pragma unroll
        for (int it = 0; it < 2; ++it)
#pragma unroll
          for (int ks = 0; ks < 2; ++ks)
            a[npar][it][ks] = *reinterpret_cast<const half8*>(
                gA + (size_t)it * 8192 + ((ks * 2 + lh) * 32 + l31) * 8);
      }
      SCB;
      half8 b[4][2];
#pragma unroll
      for (int jt = 0; jt < 4; ++jt)
#pragma unroll
        for (int ks = 0; ks < 2; ++ks)
          b[jt][ks] = *reinterpret_cast<const half8*>(
              ldsB + kc * 4096 + ((jt * 2 + ks) * 2 + lh) * 256 + l31 * 8);
      __builtin_amdgcn_s_setprio(1);
#pragma unroll
      for (int ks = 0; ks < 2; ++ks)
#pragma unroll
        for (int it = 0; it < 2; ++it)
#pragma unroll
          for (int jt = 0; jt < 4; ++jt)
            acc[it][jt] = MFMA16(a[par][it][ks], b[jt][ks], acc[it][jt]);
      __builtin_amdgcn_s_setprio(0);
    }

#pragma unroll
    for (int it = 0; it < 2; ++it) {
      const int code0 = (t0 + it) * 32;
      const float* ep = en2 + code0 + 4 * lh;
      const float4 e0 = *reinterpret_cast<const float4*>(ep);
      const float4 e1 = *reinterpret_cast<const float4*>(ep + 8);
      const float4 e2 = *reinterpret_cast<const float4*>(ep + 16);
      const float4 e3 = *reinterpret_cast<const float4*>(ep + 24);
      const float ev[16] = {e0.x, e0.y, e0.z, e0.w, e1.x, e1.y, e1.z, e1.w,
                            e2.x, e2.y, e2.z, e2.w, e3.x, e3.y, e3.z, e3.w};
#pragma unroll
      for (int reg = 0; reg < 16; ++reg) {
        const int code = code0 + (reg & 3) + 8 * (reg >> 2) + 4 * lh;
#pragma unroll
        for (int jt = 0; jt < 4; ++jt) {
          const float v = acc[it][jt][reg] - ev[reg];
          b2[jt] = fmaxf(b2[jt], fminf(v, b1[jt]));
          i1[jt] = (v > b1[jt]) ? code : i1[jt];
          b1[jt] = fmaxf(b1[jt], v);
        }
      }
    }
  }

  // merge lane <-> lane^32 (same rows, disjoint codes)
#pragma unroll
  for (int jt = 0; jt < 4; ++jt) {
    const float o1 = __shfl_xor(b1[jt], 32, 64);
    const int oi = __shfl_xor(i1[jt], 32, 64);
    const float o2 = __shfl_xor(b2[jt], 32, 64);
    const float lose = fminf(b1[jt], o1);
    i1[jt] = (b1[jt] >= o1) ? i1[jt] : oi;
    b1[jt] = fmaxf(b1[jt], o1);
    b2[jt] = fmaxf(fmaxf(b2[jt], o2), lose);
  }

  if (lane < 32) {
    const int split = cs * 4 + wv;
#pragma unroll
    for (int jt = 0; jt < 4; ++jt) {
      const int row = bx * 128 + jt * 32 + l31;
      candV[(size_t)split * M_ROWS + row] = b1[jt];
      candI[(size_t)split * M_ROWS + row] = i1[jt];
      cand2[(size_t)split * M_ROWS + row] = b2[jt];
    }
  }
}

// ---- merge 16 splits -> packed key; enqueue risky rows onto per-split lists ----
__global__ void vq_reduce(const float* __restrict__ candV, const int* __restrict__ candI,
                          const float* __restrict__ cand2, int* __restrict__ cntS,
                          int* __restrict__ riskyS, unsigned long long* __restrict__ key) {
  const int row = blockIdx.x * 256 + threadIdx.x;
  float v[NSPLIT];
#pragma unroll
  for (int s = 0; s < NSPLIT; ++s) v[s] = candV[(size_t)s * M_ROWS + row];
  float b1 = v[0];
  int i1 = candI[row];
  float b2 = cand2[row];
#pragma unroll
  for (int s = 1; s < NSPLIT; ++s) {
    const int ii = candI[(size_t)s * M_ROWS + row];
    const float v2 = cand2[(size_t)s * M_ROWS + row];
    const float lose = fminf(b1, v[s]);
    i1 = (v[s] > b1) ? ii : i1;
    b1 = fmaxf(b1, v[s]);
    b2 = fmaxf(fmaxf(b2, v2), lose);
  }
  if (b1 - b2 < TAU) {
    key[row] = 0ull;
    const float thr = b1 - TAU;
#pragma unroll
    for (int s = 0; s < NSPLIT; ++s) {
      if (v[s] > thr) {
        const int p = atomicAdd(&cntS[s], 1);
        riskyS[(size_t)s * SCAP + p] = row;
      }
    }
  } else {
    unsigned u = __float_as_uint(b1);
    u ^= (u >> 31) ? 0xFFFFFFFFu : 0x80000000u;
    key[row] = ((unsigned long long)u << 32) | (unsigned)(N_CODES - 1 - i1);
  }
}

// ---- exact fp32 rescore, split-filtered, 4 row-stripes ----
__global__ __launch_bounds__(256)
void vq_refine(const float* __restrict__ x, const float* __restrict__ cb,
               const float* __restrict__ en2, const int* __restrict__ cntS,
               const int* __restrict__ riskyS, unsigned long long* __restrict__ key) {
  __shared__ float cbs[32][260];
  __shared__ float xs[8][260];
  __shared__ int rowS[8];
  const int split = blockIdx.x >> 4;
  const int n = cntS[split];
  if (n == 0) return;
  const int tid = threadIdx.x;
  const int cBase = split * 512 + (blockIdx.x & 15) * 32;
  const int* list = riskyS + (size_t)split * SCAP;
  const int cl = tid >> 3, rs = tid & 7;
#pragma unroll
  for (int q = 0; q < 32; ++q) cbs[q][tid] = cb[(size_t)(cBase + q) * K_DIM + tid];
  const float e_c = en2[cBase + cl];
  for (int t0 = blockIdx.y * 8; t0 < n; t0 += 32) {
    __syncthreads();
    if (tid < 8) {
      const int ti = t0 + tid;
      rowS[tid] = list[ti < n ? ti : n - 1];
    }
    __syncthreads();
#pragma unroll
    for (int r = 0; r < 8; ++r) xs[r][tid] = x[(size_t)rowS[r] * K_DIM + tid];
    __syncthreads();
    float s0 = 0.f, s1 = 0.f;
#pragma unroll 4
    for (int k4 = 0; k4 < 64; k4 += 2) {
      const float4 c0 = *reinterpret_cast<const float4*>(&cbs[cl][k4 * 4]);
      const float4 x0 = *reinterpret_cast<const float4*>(&xs[rs][k4 * 4]);
      const float4 c1 = *reinterpret_cast<const float4*>(&cbs[cl][k4 * 4 + 4]);
      const float4 x1 = *reinterpret_cast<const float4*>(&xs[rs][k4 * 4 + 4]);
      s0 = fmaf(x0.x, c0.x, s0); s0 = fmaf(x0.y, c0.y, s0);
      s0 = fmaf(x0.z, c0.z, s0); s0 = fmaf(x0.w, c0.w, s0);
      s1 = fmaf(x1.x, c1.x, s1); s1 = fmaf(x1.y, c1.y, s1);
      s1 = fmaf(x1.z, c1.z, s1); s1 = fmaf(x1.w, c1.w, s1);
    }
    const float sc = (s0 + s1) - e_c;
    unsigned u = __float_as_uint(sc);
    u ^= (u >> 31) ? 0xFFFFFFFFu : 0x80000000u;
    unsigned long long k64 =
        ((unsigned long long)u << 32) | (unsigned)(N_CODES - 1 - (cBase + cl));
    {
      unsigned long long o;
      o = __shfl_xor(k64, 8, 64);  if (o > k64) k64 = o;
      o = __shfl_xor(k64, 16, 64); if (o > k64) k64 = o;
      o = __shfl_xor(k64, 32, 64); if (o > k64) k64 = o;
    }
    if (((tid >> 3) & 7) == 0) atomicMax(key + rowS[rs], k64);
  }
}

// ---- gather z_q from key, write z_q_st + indices (no x read, no reduction) ----
__global__ void vq_gather(const float* __restrict__ cb,
                          const unsigned long long* __restrict__ key,
                          float* __restrict__ zq, float* __restrict__ idxf) {
  const int g = blockIdx.x * 256 + threadIdx.x;
  const int row = g >> 6;
  const int c4 = g & 63;
  const int idx = N_CODES - 1 - (int)(unsigned)(key[row] & 0xFFFFFFFFull);
  if (c4 == 0) idxf[row] = (float)idx;
  const float4 z = *reinterpret_cast<const float4*>(cb + (size_t)idx * K_DIM + c4 * 4);
  *reinterpret_cast<float4*>(zq + (size_t)g * 4) = z;
}

// ---- analytic loss: sum over rows of (||x||^2 - 2*score) ----
// score decoded from key's monotone-encoded top-32 bits.
__global__ void vq_loss(const unsigned long long* __restrict__ key,
                        const float* __restrict__ xn, float* __restrict__ out) {
  __shared__ float red[256];
  const int tid = threadIdx.x;
  float s = 0.f;
  for (int i = 0; i < 64; ++i) {
    const int row = i * 256 + tid;
    const unsigned eu = (unsigned)(key[row] >> 32);
    const unsigned fu = (eu & 0x80000000u) ? (eu ^ 0x80000000u) : ~eu;
    s += xn[row] - 2.0f * __uint_as_float(fu);
  }
  red[tid] = s;
  __syncthreads();
  for (int o = 128; o > 0; o >>= 1) {
    if (tid < o) red[tid] += red[tid + o];
    __syncthreads();
  }
  if (tid == 0) out[0] = 1.25f * red[0] / 4194304.0f;
}

extern "C" void kernel_launch(void* const* d_in, const int* in_sizes, int n_in,
                              void* d_out, int out_size, void* d_ws, size_t ws_size,
                              hipStream_t stream) {
  const float* x = (const float*)d_in[0];
  const float* cb = (const float*)d_in[1];
  float* out = (float*)d_out;
  float* zq = out;
  float* loss = out + 4194304;
  float* idxf = out + 4194305;

  char* w = (char*)d_ws;
  _Float16* Apack = (_Float16*)w;                      w += (size_t)N_CODES * K_DIM * 2;   // 4MB h
  _Float16* Bpack = (_Float16*)w;                      w += (size_t)M_ROWS * K_DIM * 2;    // 8MB h
  unsigned long long* key = (unsigned long long*)w;    w += (size_t)M_ROWS * 8;
  float* en2 = (float*)w;                              w += (size_t)N_CODES * 4;
  float* xn = (float*)w;                               w += (size_t)M_ROWS * 4;
  float* candV = (float*)w;                            w += (size_t)M_ROWS * NSPLIT * 4;
  float* cand2 = (float*)w;                            w += (size_t)M_ROWS * NSPLIT * 4;
  int* candI = (int*)w;                                w += (size_t)M_ROWS * NSPLIT * 4;
  int* riskyS = (int*)w;                               w += (size_t)NSPLIT * SCAP * 4;     // 1MB
  int* cntS = (int*)w;                                 w += 64;

  pack_all<<<3072, 256, 0, stream>>>(x, cb, Apack, Bpack, en2, xn, cntS);
  vq_dist<<<512, 256, 0, stream>>>(Apack, Bpack, en2, candV, candI, cand2);
  vq_reduce<<<M_ROWS / 256, 256, 0, stream>>>(candV, candI, cand2, cntS, riskyS, key);
  vq_refine<<<dim3(256, 4), 256, 0, stream>>>(x, cb, en2, cntS, riskyS, key);
  vq_gather<<<4194304 / (256 * 4), 256, 0, stream>>>(cb, key, zq, idxf);
  vq_loss<<<1, 256, 0, stream>>>(key, xn, loss);
}